// Round 3
// baseline (268.742 us; speedup 1.0000x reference)
//
#include <hip/hip_runtime.h>

#define NBINS 2048
#define B 4
#define C 16
#define HID 32
#define NI 32
#define INTER 36864           // 192*192 interior pixels per image
#define PADMULT 28672         // 256*256 - 192*192 padded pixels per instance
#define EPSF 1e-6f
#define THR 512

// ---- ws layout (uint units). Control region is fixed; histogram region is
// parameterized by runtime HB (partial-histogram blocks per image).
#define OFF_COUNTS 0                      // [B][NI] float
#define OFF_CSUMS  (OFF_COUNTS + B*NI)    // [B][NI][C] float
#define OFF_V      (OFF_CSUMS + B*NI*C)   // [B][NI][HID] float
#define OFF_PERR   (OFF_V + B*NI*HID)     // [B][NI] float
#define OFF_MINK   (OFF_PERR + B*NI)      // [B] uint (mapped float, min)
#define OFF_MAXK   (OFF_MINK + B)         // [B] uint (mapped float, max)
#define OFF_VMAX   (OFF_MAXK + B)         // [B][HID] float: max_n v[n,k]
#define CTRL_END   (OFF_VMAX + B*HID)
#define OFF_HCNT   8192                   // [B][HB][NBINS] uint packed cnt|pos<<16

__device__ __host__ inline size_t off_hsum(int hb) { return OFF_HCNT + (size_t)B * hb * NBINS; }
__device__ __host__ inline size_t off_fcnt(int hb) { return off_hsum(hb) + (size_t)B * hb * NBINS; }
__device__ __host__ inline size_t off_fpos(int hb) { return off_fcnt(hb) + (size_t)B * NBINS; }
__device__ __host__ inline size_t off_fsum(int hb) { return off_fpos(hb) + (size_t)B * NBINS; }
__device__ __host__ inline size_t ws_need(int hb)  { return (off_fsum(hb) + (size_t)B * NBINS) * 4; }

__device__ inline unsigned fmap(float f) {
    unsigned u = __float_as_uint(f);
    return (u & 0x80000000u) ? ~u : (u | 0x80000000u);
}
__device__ inline float funmap(unsigned k) {
    return (k & 0x80000000u) ? __uint_as_float(k & 0x7fffffffu)
                             : __uint_as_float(~k);
}

// Kernel 1: weighted per-instance counts and embedding sums (interior only;
// padding contributes zero because padded w == 0).
__global__ void k_counts(const float* emb, const float* wgt, const int* gt,
                         float* ws) {
    __shared__ float s_cnt[NI];
    __shared__ float s_sum[NI * C];
    int tid = threadIdx.x;
    int img = blockIdx.y;
    for (int i = tid; i < NI; i += 256) s_cnt[i] = 0.f;
    for (int i = tid; i < NI * C; i += 256) s_sum[i] = 0.f;
    __syncthreads();
    int p = blockIdx.x * 256 + tid;  // 144 blocks * 256 == 36864 exactly
    int g = gt[img * INTER + p];
    if (g > 0 && g <= NI) {
        float wv = wgt[img * INTER + p];
        atomicAdd(&s_cnt[g - 1], wv);
        const float* e = emb + (size_t)img * C * INTER + p;
        #pragma unroll
        for (int c = 0; c < C; c++)
            atomicAdd(&s_sum[(g - 1) * C + c], e[c * INTER] * wv);
    }
    __syncthreads();
    for (int i = tid; i < NI; i += 256)
        atomicAdd(&ws[OFF_COUNTS + img * NI + i], s_cnt[i]);
    for (int i = tid; i < NI * C; i += 256)
        atomicAdd(&ws[OFF_CSUMS + (img * NI) * C + i], s_sum[i]);
}

// Kernel 2: v[n,k] = centers.W1 + b1; vmax[k] = max_n v[n,k]; pad-region
// error per instance (emb==0, label==0): perr[n] = 1 + MLP(v[n]); fold pad
// errors into the global min/max keys.
__global__ void k_centers(const float* W1, const float* b1, const float* W2,
                          const float* b2, float* ws, unsigned* wsu) {
    int img = blockIdx.x;
    int tid = threadIdx.x;
    __shared__ float s_v[NI * HID];
    for (int idx = tid; idx < NI * HID; idx += 256) {
        int n = idx >> 5, k = idx & 31;
        float cnt = ws[OFF_COUNTS + img * NI + n] + EPSF;
        float acc = b1[k];
        #pragma unroll
        for (int c = 0; c < C; c++)
            acc += (ws[OFF_CSUMS + (img * NI + n) * C + c] / cnt) * W1[c * HID + k];
        s_v[idx] = acc;
        ws[OFF_V + (img * NI + n) * HID + k] = acc;
    }
    __syncthreads();
    if (tid < HID) {
        float m = -1e30f;
        #pragma unroll
        for (int n = 0; n < NI; n++) m = fmaxf(m, s_v[n * HID + tid]);
        ws[OFF_VMAX + img * HID + tid] = m;
    }
    if (tid < NI) {
        float lg = b2[0];
        #pragma unroll
        for (int k = 0; k < HID; k++)
            lg += fmaxf(s_v[tid * HID + k], 0.f) * W2[k];
        float pe = 1.f + lg;           // label = 0 in padding
        ws[OFF_PERR + img * NI + tid] = pe;
        unsigned key = fmap(pe);
        atomicMin(&wsu[OFF_MINK + img], key);
        atomicMax(&wsu[OFF_MAXK + img], key);
    }
}

// Kernel 3: analytic per-pixel error bounds (NO per-instance loop).
// relu is monotone, so relu(v[n,k]-u[k]) in [0, relu(vmax[k]-u[k])], giving
// lg in [lo,hi] with only O(HID) work per pixel. err in {1-lg, 1+lg} subset
// [min(1-hi,1+lo), max(1-lo,1+hi)]. Bins only need to COVER the data; the
// per-bin exact mean keeps accuracy independent of the bound's slack.
__global__ void k_bound(const float* emb, const float* W1, const float* W2,
                        const float* b2, const float* ws, unsigned* wsu) {
    int img = blockIdx.y, tid = threadIdx.x;
    __shared__ float s_w1[C * HID];
    __shared__ float s_vmax[HID];
    __shared__ float s_w2[HID];
    __shared__ unsigned bmin, bmax;
    for (int i = tid; i < C * HID; i += THR) s_w1[i] = W1[i];
    if (tid < HID) {
        s_vmax[tid] = ws[OFF_VMAX + img * HID + tid];
        s_w2[tid] = W2[tid];
    }
    if (tid == 0) { bmin = 0xFFFFFFFFu; bmax = 0u; }
    __syncthreads();
    int p = blockIdx.x * THR + tid;   // 72 blocks * 512 == 36864
    const float* ep = emb + (size_t)img * C * INTER + p;
    float u[HID];
    #pragma unroll
    for (int k = 0; k < HID; k++) u[k] = 0.f;
    #pragma unroll
    for (int c = 0; c < C; c++) {
        float ev = ep[c * INTER];
        #pragma unroll
        for (int k = 0; k < HID; k++) u[k] = fmaf(ev, s_w1[c * HID + k], u[k]);
    }
    float b2v = b2[0];
    float hi = b2v, lo = b2v;
    #pragma unroll
    for (int k = 0; k < HID; k++) {
        float t = fmaxf(s_vmax[k] - u[k], 0.f);
        float w = s_w2[k];
        hi = fmaf(fmaxf(w, 0.f), t, hi);
        lo = fmaf(fminf(w, 0.f), t, lo);
    }
    float elo = fminf(1.f - hi, 1.f + lo);
    float ehi = fmaxf(1.f - lo, 1.f + hi);
    atomicMin(&bmin, fmap(elo));
    atomicMax(&bmax, fmap(ehi));
    __syncthreads();
    if (tid == 0) {
        atomicMin(&wsu[OFF_MINK + img], bmin);
        atomicMax(&wsu[OFF_MAXK + img], bmax);
    }
}

// Kernel 4: LDS-private histogram per block, flushed with plain stores to a
// per-block global partial region. Packed cnt|pos<<16 per bin (block-local
// cnt <= 32*ppb < 65536). Per-bin sum(relu(err)) kept for exact means.
__global__ void k_hist(const float* emb, const int* gt, const float* W1,
                       const float* W2, const float* b2, const float* ws,
                       unsigned* wsu, int hb, int ppb) {
    int img = blockIdx.y, bx = blockIdx.x, tid = threadIdx.x;
    __shared__ float s_v[NI * HID];   // 4 KB
    __shared__ float s_w1[C * HID];   // 2 KB
    __shared__ float s_w2[HID];
    __shared__ unsigned s_h[NBINS];   // 8 KB
    __shared__ float s_s[NBINS];      // 8 KB
    for (int i = tid; i < NI * HID; i += THR) s_v[i] = ws[OFF_V + img * NI * HID + i];
    for (int i = tid; i < C * HID; i += THR) s_w1[i] = W1[i];
    if (tid < HID) s_w2[tid] = W2[tid];
    for (int i = tid; i < NBINS; i += THR) { s_h[i] = 0u; s_s[i] = 0.f; }
    float emax = funmap(wsu[OFF_MAXK + img]);
    float emin = funmap(wsu[OFF_MINK + img]);
    float invbw = (float)NBINS / fmaxf(emax - emin, 1e-20f);
    float b2v = b2[0];
    __syncthreads();

    int base = bx * ppb;
    for (int i = tid; i < ppb; i += THR) {
        int p = base + i;
        const float* ep = emb + (size_t)img * C * INTER + p;
        float u[HID];
        #pragma unroll
        for (int k = 0; k < HID; k++) u[k] = 0.f;
        #pragma unroll
        for (int c = 0; c < C; c++) {
            float ev = ep[c * INTER];
            #pragma unroll
            for (int k = 0; k < HID; k++) u[k] = fmaf(ev, s_w1[c * HID + k], u[k]);
        }
        int g = gt[img * INTER + p];
        for (int n = 0; n < NI; n++) {
            float lg = b2v;
            #pragma unroll
            for (int k = 0; k < HID; k++)
                lg = fmaf(fmaxf(s_v[n * HID + k] - u[k], 0.f), s_w2[k], lg);
            bool pos = (g == n + 1);
            float err = pos ? (1.f - lg) : (1.f + lg);
            int bn = (int)((emax - err) * invbw);
            bn = bn < 0 ? 0 : (bn >= NBINS ? NBINS - 1 : bn);
            atomicAdd(&s_h[bn], pos ? 0x10001u : 1u);
            atomicAdd(&s_s[bn], fmaxf(err, 0.f));
        }
    }
    __syncthreads();
    unsigned* gc = wsu + OFF_HCNT + (size_t)(img * hb + bx) * NBINS;
    float* gs = (float*)wsu + off_hsum(hb) + (size_t)(img * hb + bx) * NBINS;
    for (int i = tid; i < NBINS; i += THR) { gc[i] = s_h[i]; gs[i] = s_s[i]; }
}

// Kernel 5: collapse the hb partial histograms into one per image (coalesced,
// parallel across 32 blocks).
__global__ void k_reduce(const float* ws, unsigned* wsu, int hb) {
    int img = blockIdx.y;
    int bn = blockIdx.x * 256 + threadIdx.x;
    unsigned cnt = 0, pos = 0;
    float sm = 0.f;
    for (int r = 0; r < hb; r++) {
        unsigned pk = wsu[OFF_HCNT + (size_t)(img * hb + r) * NBINS + bn];
        cnt += pk & 0xFFFFu;
        pos += pk >> 16;
        sm += ws[off_hsum(hb) + (size_t)(img * hb + r) * NBINS + bn];
    }
    wsu[off_fcnt(hb) + (size_t)img * NBINS + bn] = cnt;
    wsu[off_fpos(hb) + (size_t)img * NBINS + bn] = pos;
    ((float*)wsu)[off_fsum(hb) + (size_t)img * NBINS + bn] = sm;
}

// Kernel 6: per-image -- add pad contributions, log-step prefix scan, Lovasz
// loss scan in double precision, mean over B into out.
__global__ void k_loss(const float* ws, const unsigned* wsu, float* out, int hb) {
    const int T = 256;
    const int CHUNK = NBINS / T;  // 8
    int img = blockIdx.x, tid = threadIdx.x;
    __shared__ unsigned s_cnt[NBINS], s_pos[NBINS];  // 16 KB
    __shared__ float s_sum[NBINS];                   // 8 KB
    __shared__ unsigned s_pc[T], s_pp[T];
    __shared__ double s_a[T];

    for (int i = tid; i < NBINS; i += T) {
        s_cnt[i] = wsu[off_fcnt(hb) + (size_t)img * NBINS + i];
        s_pos[i] = wsu[off_fpos(hb) + (size_t)img * NBINS + i];
        s_sum[i] = ((const float*)wsu)[off_fsum(hb) + (size_t)img * NBINS + i];
    }
    float emax = funmap(wsu[OFF_MAXK + img]);
    float emin = funmap(wsu[OFF_MINK + img]);
    float invbw = (float)NBINS / fmaxf(emax - emin, 1e-20f);
    __syncthreads();

    // pad-region: each (img,n) pad error occurs PADMULT times, label 0.
    if (tid < NI) {
        float pe = ws[OFF_PERR + img * NI + tid];
        int bn = (int)((emax - pe) * invbw);
        bn = bn < 0 ? 0 : (bn >= NBINS ? NBINS - 1 : bn);
        atomicAdd(&s_cnt[bn], (unsigned)PADMULT);
        atomicAdd(&s_sum[bn], (float)PADMULT * fmaxf(pe, 0.f));
    }
    __syncthreads();

    // per-thread chunk totals, then Hillis-Steele inclusive scan
    unsigned ccnt = 0, cpos = 0;
    for (int j = 0; j < CHUNK; j++) {
        int bn = tid * CHUNK + j;
        ccnt += s_cnt[bn]; cpos += s_pos[bn];
    }
    s_pc[tid] = ccnt; s_pp[tid] = cpos;
    __syncthreads();
    for (int off = 1; off < T; off <<= 1) {
        unsigned ac = 0, ap = 0;
        if (tid >= off) { ac = s_pc[tid - off]; ap = s_pp[tid - off]; }
        __syncthreads();
        s_pc[tid] += ac; s_pp[tid] += ap;
        __syncthreads();
    }
    double Gd = (double)s_pp[T - 1];
    double r = (double)(s_pc[tid] - ccnt), L = (double)(s_pp[tid] - cpos);

    double Jprev = 1.0 - (Gd - L) / (Gd + r - L);
    double acc = 0.0;
    for (int j = 0; j < CHUNK; j++) {
        int bn = tid * CHUNK + j;
        unsigned cv = s_cnt[bn], pv = s_pos[bn];
        if (cv) {
            r += (double)cv; L += (double)pv;
            double J = 1.0 - (Gd - L) / (Gd + r - L);
            double mean = (double)s_sum[bn] / (double)cv;  // exact in-bin mean
            acc += mean * (J - Jprev);
            Jprev = J;
        }
    }
    s_a[tid] = acc;
    __syncthreads();
    for (int s = T / 2; s > 0; s >>= 1) {
        if (tid < s) s_a[tid] += s_a[tid + s];
        __syncthreads();
    }
    if (tid == 0) atomicAdd(out, (float)(s_a[0] * 0.25));  // mean over B=4
}

extern "C" void kernel_launch(void* const* d_in, const int* in_sizes, int n_in,
                              void* d_out, int out_size, void* d_ws, size_t ws_size,
                              hipStream_t stream) {
    const float* emb = (const float*)d_in[0];
    const float* wgt = (const float*)d_in[1];
    const int*   gt  = (const int*)d_in[2];
    const float* W1  = (const float*)d_in[3];
    const float* b1  = (const float*)d_in[4];
    const float* W2  = (const float*)d_in[5];
    const float* b2  = (const float*)d_in[6];
    float* out = (float*)d_out;
    float* ws  = (float*)d_ws;
    unsigned* wsu = (unsigned*)d_ws;

    // HB=72 needs 4.85 MB of ws; fall back to HB=36 (2.5 MB, proven safe)
    // if the harness scratch is small. ws_size is fixed -> deterministic.
    int hb = (ws_size >= ws_need(72)) ? 72 : 36;
    int ppb = INTER / hb;

    hipMemsetAsync(d_ws, 0, (size_t)CTRL_END * 4, stream);
    hipMemsetAsync((char*)d_ws + (size_t)OFF_MINK * 4, 0xFF, B * 4, stream);
    hipMemsetAsync(d_out, 0, sizeof(float), stream);

    dim3 g1(INTER / 256, B);
    k_counts<<<g1, 256, 0, stream>>>(emb, wgt, gt, ws);
    k_centers<<<B, 256, 0, stream>>>(W1, b1, W2, b2, ws, wsu);
    dim3 gb(INTER / THR, B);
    k_bound<<<gb, THR, 0, stream>>>(emb, W1, W2, b2, ws, wsu);
    dim3 gh(hb, B);
    k_hist<<<gh, THR, 0, stream>>>(emb, gt, W1, W2, b2, ws, wsu, hb, ppb);
    dim3 gr(NBINS / 256, B);
    k_reduce<<<gr, 256, 0, stream>>>(ws, wsu, hb);
    k_loss<<<B, 256, 0, stream>>>(ws, wsu, out, hb);
}

// Round 4
// 206.755 us; speedup vs baseline: 1.2998x; 1.2998x over previous
//
#include <hip/hip_runtime.h>

#define NBINS 2048
#define B 4
#define C 16
#define HID 32
#define NI 32
#define INTER 36864           // 192*192 interior pixels per image
#define PADMULT 28672         // 256*256 - 192*192 padded pixels per instance
#define EPSF 1e-6f
#define THR 512

// ---- ws layout (uint units). Control region is fixed; histogram region is
// parameterized by HB (partial-histogram blocks per image).
#define OFF_COUNTS 0                      // [B][NI] float
#define OFF_CSUMS  (OFF_COUNTS + B*NI)    // [B][NI][C] float
#define OFF_V      (OFF_CSUMS + B*NI*C)   // [B][NI][HID] float
#define OFF_PERR   (OFF_V + B*NI*HID)     // [B][NI] float
#define OFF_MINK   (OFF_PERR + B*NI)      // [B] uint (mapped float, min)
#define OFF_MAXK   (OFF_MINK + B)         // [B] uint (mapped float, max)
#define OFF_VMAX   (OFF_MAXK + B)         // [B][HID] float: max_n v[n,k]
#define CTRL_END   (OFF_VMAX + B*HID)
#define OFF_HCNT   8192                   // [B][HB][NBINS] uint packed cnt|pos<<16

__device__ __host__ inline size_t off_hsum(int hb) { return OFF_HCNT + (size_t)B * hb * NBINS; }
__device__ __host__ inline size_t off_fcnt(int hb) { return off_hsum(hb) + (size_t)B * hb * NBINS; }
__device__ __host__ inline size_t off_fpos(int hb) { return off_fcnt(hb) + (size_t)B * NBINS; }
__device__ __host__ inline size_t off_fsum(int hb) { return off_fpos(hb) + (size_t)B * NBINS; }
__device__ __host__ inline size_t ws_need(int hb)  { return (off_fsum(hb) + (size_t)B * NBINS) * 4; }

__device__ inline unsigned fmap(float f) {
    unsigned u = __float_as_uint(f);
    return (u & 0x80000000u) ? ~u : (u | 0x80000000u);
}
__device__ inline float funmap(unsigned k) {
    return (k & 0x80000000u) ? __uint_as_float(k & 0x7fffffffu)
                             : __uint_as_float(~k);
}

// Kernel 1: weighted per-instance counts and embedding sums (interior only;
// padding contributes zero because padded w == 0).
__global__ __launch_bounds__(256, 4) void k_counts(const float* emb, const float* wgt,
                                                   const int* gt, float* ws) {
    __shared__ float s_cnt[NI];
    __shared__ float s_sum[NI * C];
    int tid = threadIdx.x;
    int img = blockIdx.y;
    for (int i = tid; i < NI; i += 256) s_cnt[i] = 0.f;
    for (int i = tid; i < NI * C; i += 256) s_sum[i] = 0.f;
    __syncthreads();
    int p = blockIdx.x * 256 + tid;  // 144 blocks * 256 == 36864 exactly
    int g = gt[img * INTER + p];
    if (g > 0 && g <= NI) {
        float wv = wgt[img * INTER + p];
        atomicAdd(&s_cnt[g - 1], wv);
        const float* e = emb + (size_t)img * C * INTER + p;
        #pragma unroll
        for (int c = 0; c < C; c++)
            atomicAdd(&s_sum[(g - 1) * C + c], e[c * INTER] * wv);
    }
    __syncthreads();
    for (int i = tid; i < NI; i += 256)
        atomicAdd(&ws[OFF_COUNTS + img * NI + i], s_cnt[i]);
    for (int i = tid; i < NI * C; i += 256)
        atomicAdd(&ws[OFF_CSUMS + (img * NI) * C + i], s_sum[i]);
}

// Kernel 2: v[n,k] = centers.W1 + b1; vmax[k] = max_n v[n,k]; pad-region
// error per instance (emb==0, label==0): perr[n] = 1 + MLP(v[n]); fold pad
// errors into the global min/max keys.
__global__ void k_centers(const float* W1, const float* b1, const float* W2,
                          const float* b2, float* ws, unsigned* wsu) {
    int img = blockIdx.x;
    int tid = threadIdx.x;
    __shared__ float s_v[NI * HID];
    for (int idx = tid; idx < NI * HID; idx += 256) {
        int n = idx >> 5, k = idx & 31;
        float cnt = ws[OFF_COUNTS + img * NI + n] + EPSF;
        float acc = b1[k];
        #pragma unroll
        for (int c = 0; c < C; c++)
            acc += (ws[OFF_CSUMS + (img * NI + n) * C + c] / cnt) * W1[c * HID + k];
        s_v[idx] = acc;
        ws[OFF_V + (img * NI + n) * HID + k] = acc;
    }
    __syncthreads();
    if (tid < HID) {
        float m = -1e30f;
        #pragma unroll
        for (int n = 0; n < NI; n++) m = fmaxf(m, s_v[n * HID + tid]);
        ws[OFF_VMAX + img * HID + tid] = m;
    }
    if (tid < NI) {
        float lg = b2[0];
        #pragma unroll
        for (int k = 0; k < HID; k++)
            lg += fmaxf(s_v[tid * HID + k], 0.f) * W2[k];
        float pe = 1.f + lg;           // label = 0 in padding
        ws[OFF_PERR + img * NI + tid] = pe;
        unsigned key = fmap(pe);
        atomicMin(&wsu[OFF_MINK + img], key);
        atomicMax(&wsu[OFF_MAXK + img], key);
    }
}

// Kernel 3: analytic per-pixel error bounds (NO per-instance loop).
// relu monotone => relu(v[n,k]-u[k]) in [0, relu(vmax[k]-u[k])] => lg in
// [lo,hi] with O(HID) work. Bins only need to COVER the data; per-bin exact
// means keep accuracy independent of the bound's slack.
__global__ __launch_bounds__(THR, 4) void k_bound(const float* emb, const float* W1,
                                                  const float* W2, const float* b2,
                                                  const float* ws, unsigned* wsu) {
    int img = blockIdx.y, tid = threadIdx.x;
    __shared__ float s_w1[C * HID];
    __shared__ float s_vmax[HID];
    __shared__ float s_w2[HID];
    __shared__ unsigned bmin, bmax;
    for (int i = tid; i < C * HID; i += THR) s_w1[i] = W1[i];
    if (tid < HID) {
        s_vmax[tid] = ws[OFF_VMAX + img * HID + tid];
        s_w2[tid] = W2[tid];
    }
    if (tid == 0) { bmin = 0xFFFFFFFFu; bmax = 0u; }
    __syncthreads();
    int p = blockIdx.x * THR + tid;   // 72 blocks * 512 == 36864
    const float* ep = emb + (size_t)img * C * INTER + p;
    float u[HID];
    #pragma unroll
    for (int k = 0; k < HID; k++) u[k] = 0.f;
    #pragma unroll
    for (int c = 0; c < C; c++) {
        float ev = ep[c * INTER];
        #pragma unroll
        for (int k = 0; k < HID; k++) u[k] = fmaf(ev, s_w1[c * HID + k], u[k]);
    }
    float b2v = b2[0];
    float hi = b2v, lo = b2v;
    #pragma unroll
    for (int k = 0; k < HID; k++) {
        float t = fmaxf(s_vmax[k] - u[k], 0.f);
        float w = s_w2[k];
        hi = fmaf(fmaxf(w, 0.f), t, hi);
        lo = fmaf(fminf(w, 0.f), t, lo);
    }
    float elo = fminf(1.f - hi, 1.f + lo);
    float ehi = fmaxf(1.f - lo, 1.f + hi);
    atomicMin(&bmin, fmap(elo));
    atomicMax(&bmax, fmap(ehi));
    __syncthreads();
    if (tid == 0) {
        atomicMin(&wsu[OFF_MINK + img], bmin);
        atomicMax(&wsu[OFF_MAXK + img], bmax);
    }
}

// Kernel 4: LDS-private histogram per block, flushed with plain stores.
// __launch_bounds__(512,4) caps VGPR at 128 -- round 3's unbounded 512-thread
// version got capped at 64 VGPRs and spilled u[32] to scratch (154 MB of
// HBM writes). Compile-time HB keeps the pixel loop fully unrolled; 4
// accumulators break the 32-deep dependent FMA chain.
template <int HB>
__global__ __launch_bounds__(THR, 4) void k_hist(const float* emb, const int* gt,
                                                 const float* W1, const float* W2,
                                                 const float* b2, const float* ws,
                                                 unsigned* wsu) {
    constexpr int PPB = INTER / HB;
    constexpr int ITER = PPB / THR;
    int img = blockIdx.y, bx = blockIdx.x, tid = threadIdx.x;
    __shared__ float s_v[NI * HID];   // 4 KB
    __shared__ float s_w1[C * HID];   // 2 KB
    __shared__ float s_w2[HID];
    __shared__ unsigned s_h[NBINS];   // 8 KB
    __shared__ float s_s[NBINS];      // 8 KB
    for (int i = tid; i < NI * HID; i += THR) s_v[i] = ws[OFF_V + img * NI * HID + i];
    for (int i = tid; i < C * HID; i += THR) s_w1[i] = W1[i];
    if (tid < HID) s_w2[tid] = W2[tid];
    for (int i = tid; i < NBINS; i += THR) { s_h[i] = 0u; s_s[i] = 0.f; }
    float emax = funmap(wsu[OFF_MAXK + img]);
    float emin = funmap(wsu[OFF_MINK + img]);
    float invbw = (float)NBINS / fmaxf(emax - emin, 1e-20f);
    float b2v = b2[0];
    __syncthreads();

    #pragma unroll
    for (int it = 0; it < ITER; ++it) {
        int p = bx * PPB + it * THR + tid;
        const float* ep = emb + (size_t)img * C * INTER + p;
        float u[HID];
        #pragma unroll
        for (int k = 0; k < HID; k++) u[k] = 0.f;
        #pragma unroll
        for (int c = 0; c < C; c++) {
            float ev = ep[c * INTER];
            #pragma unroll
            for (int k = 0; k < HID; k++) u[k] = fmaf(ev, s_w1[c * HID + k], u[k]);
        }
        int g = gt[img * INTER + p];
        for (int n = 0; n < NI; n++) {
            const float* vn = &s_v[n * HID];
            float lg0 = b2v, lg1 = 0.f, lg2 = 0.f, lg3 = 0.f;
            #pragma unroll
            for (int k = 0; k < HID; k += 4) {
                lg0 = fmaf(fmaxf(vn[k + 0] - u[k + 0], 0.f), s_w2[k + 0], lg0);
                lg1 = fmaf(fmaxf(vn[k + 1] - u[k + 1], 0.f), s_w2[k + 1], lg1);
                lg2 = fmaf(fmaxf(vn[k + 2] - u[k + 2], 0.f), s_w2[k + 2], lg2);
                lg3 = fmaf(fmaxf(vn[k + 3] - u[k + 3], 0.f), s_w2[k + 3], lg3);
            }
            float lg = (lg0 + lg1) + (lg2 + lg3);
            bool pos = (g == n + 1);
            float err = pos ? (1.f - lg) : (1.f + lg);
            int bn = (int)((emax - err) * invbw);
            bn = bn < 0 ? 0 : (bn >= NBINS ? NBINS - 1 : bn);
            atomicAdd(&s_h[bn], pos ? 0x10001u : 1u);
            atomicAdd(&s_s[bn], fmaxf(err, 0.f));
        }
    }
    __syncthreads();
    unsigned* gc = wsu + OFF_HCNT + (size_t)(img * HB + bx) * NBINS;
    float* gs = (float*)wsu + off_hsum(HB) + (size_t)(img * HB + bx) * NBINS;
    for (int i = tid; i < NBINS; i += THR) { gc[i] = s_h[i]; gs[i] = s_s[i]; }
}

// Kernel 5: collapse the hb partial histograms into one per image (coalesced).
__global__ void k_reduce(const float* ws, unsigned* wsu, int hb) {
    int img = blockIdx.y;
    int bn = blockIdx.x * 256 + threadIdx.x;
    unsigned cnt = 0, pos = 0;
    float sm = 0.f;
    for (int r = 0; r < hb; r++) {
        unsigned pk = wsu[OFF_HCNT + (size_t)(img * hb + r) * NBINS + bn];
        cnt += pk & 0xFFFFu;
        pos += pk >> 16;
        sm += ws[off_hsum(hb) + (size_t)(img * hb + r) * NBINS + bn];
    }
    wsu[off_fcnt(hb) + (size_t)img * NBINS + bn] = cnt;
    wsu[off_fpos(hb) + (size_t)img * NBINS + bn] = pos;
    ((float*)wsu)[off_fsum(hb) + (size_t)img * NBINS + bn] = sm;
}

// Kernel 6: per-image -- add pad contributions, log-step prefix scan, Lovasz
// loss scan in double precision, mean over B into out.
__global__ void k_loss(const float* ws, const unsigned* wsu, float* out, int hb) {
    const int T = 256;
    const int CHUNK = NBINS / T;  // 8
    int img = blockIdx.x, tid = threadIdx.x;
    __shared__ unsigned s_cnt[NBINS], s_pos[NBINS];  // 16 KB
    __shared__ float s_sum[NBINS];                   // 8 KB
    __shared__ unsigned s_pc[T], s_pp[T];
    __shared__ double s_a[T];

    for (int i = tid; i < NBINS; i += T) {
        s_cnt[i] = wsu[off_fcnt(hb) + (size_t)img * NBINS + i];
        s_pos[i] = wsu[off_fpos(hb) + (size_t)img * NBINS + i];
        s_sum[i] = ((const float*)wsu)[off_fsum(hb) + (size_t)img * NBINS + i];
    }
    float emax = funmap(wsu[OFF_MAXK + img]);
    float emin = funmap(wsu[OFF_MINK + img]);
    float invbw = (float)NBINS / fmaxf(emax - emin, 1e-20f);
    __syncthreads();

    // pad-region: each (img,n) pad error occurs PADMULT times, label 0.
    if (tid < NI) {
        float pe = ws[OFF_PERR + img * NI + tid];
        int bn = (int)((emax - pe) * invbw);
        bn = bn < 0 ? 0 : (bn >= NBINS ? NBINS - 1 : bn);
        atomicAdd(&s_cnt[bn], (unsigned)PADMULT);
        atomicAdd(&s_sum[bn], (float)PADMULT * fmaxf(pe, 0.f));
    }
    __syncthreads();

    // per-thread chunk totals, then Hillis-Steele inclusive scan
    unsigned ccnt = 0, cpos = 0;
    for (int j = 0; j < CHUNK; j++) {
        int bn = tid * CHUNK + j;
        ccnt += s_cnt[bn]; cpos += s_pos[bn];
    }
    s_pc[tid] = ccnt; s_pp[tid] = cpos;
    __syncthreads();
    for (int off = 1; off < T; off <<= 1) {
        unsigned ac = 0, ap = 0;
        if (tid >= off) { ac = s_pc[tid - off]; ap = s_pp[tid - off]; }
        __syncthreads();
        s_pc[tid] += ac; s_pp[tid] += ap;
        __syncthreads();
    }
    double Gd = (double)s_pp[T - 1];
    double r = (double)(s_pc[tid] - ccnt), L = (double)(s_pp[tid] - cpos);

    double Jprev = 1.0 - (Gd - L) / (Gd + r - L);
    double acc = 0.0;
    for (int j = 0; j < CHUNK; j++) {
        int bn = tid * CHUNK + j;
        unsigned cv = s_cnt[bn], pv = s_pos[bn];
        if (cv) {
            r += (double)cv; L += (double)pv;
            double J = 1.0 - (Gd - L) / (Gd + r - L);
            double mean = (double)s_sum[bn] / (double)cv;  // exact in-bin mean
            acc += mean * (J - Jprev);
            Jprev = J;
        }
    }
    s_a[tid] = acc;
    __syncthreads();
    for (int s = T / 2; s > 0; s >>= 1) {
        if (tid < s) s_a[tid] += s_a[tid + s];
        __syncthreads();
    }
    if (tid == 0) atomicAdd(out, (float)(s_a[0] * 0.25));  // mean over B=4
}

extern "C" void kernel_launch(void* const* d_in, const int* in_sizes, int n_in,
                              void* d_out, int out_size, void* d_ws, size_t ws_size,
                              hipStream_t stream) {
    const float* emb = (const float*)d_in[0];
    const float* wgt = (const float*)d_in[1];
    const int*   gt  = (const int*)d_in[2];
    const float* W1  = (const float*)d_in[3];
    const float* b1  = (const float*)d_in[4];
    const float* W2  = (const float*)d_in[5];
    const float* b2  = (const float*)d_in[6];
    float* out = (float*)d_out;
    float* ws  = (float*)d_ws;
    unsigned* wsu = (unsigned*)d_ws;

    // HB=72 needs 4.85 MB of ws; fall back to HB=36 (2.5 MB, proven safe)
    // if the harness scratch is small. ws_size is fixed -> deterministic.
    int hb = (ws_size >= ws_need(72)) ? 72 : 36;

    hipMemsetAsync(d_ws, 0, (size_t)CTRL_END * 4, stream);
    hipMemsetAsync((char*)d_ws + (size_t)OFF_MINK * 4, 0xFF, B * 4, stream);
    hipMemsetAsync(d_out, 0, sizeof(float), stream);

    dim3 g1(INTER / 256, B);
    k_counts<<<g1, 256, 0, stream>>>(emb, wgt, gt, ws);
    k_centers<<<B, 256, 0, stream>>>(W1, b1, W2, b2, ws, wsu);
    dim3 gb(INTER / THR, B);
    k_bound<<<gb, THR, 0, stream>>>(emb, W1, W2, b2, ws, wsu);
    if (hb == 72) {
        dim3 gh(72, B);
        k_hist<72><<<gh, THR, 0, stream>>>(emb, gt, W1, W2, b2, ws, wsu);
    } else {
        dim3 gh(36, B);
        k_hist<36><<<gh, THR, 0, stream>>>(emb, gt, W1, W2, b2, ws, wsu);
    }
    dim3 gr(NBINS / 256, B);
    k_reduce<<<gr, 256, 0, stream>>>(ws, wsu, hb);
    k_loss<<<B, 256, 0, stream>>>(ws, wsu, out, hb);
}

// Round 5
// 173.673 us; speedup vs baseline: 1.5474x; 1.1905x over previous
//
#include <hip/hip_runtime.h>

#define NBINS 2048
#define B 4
#define C 16
#define HID 32
#define NI 32
#define INTER 36864           // 192*192 interior pixels per image
#define PADMULT 28672         // 256*256 - 192*192 padded pixels per instance
#define EPSF 1e-6f
#define THR 256

// ---- ws layout (uint units).
#define OFF_COUNTS 0                      // [B][NI] float
#define OFF_CSUMS  (OFF_COUNTS + B*NI)    // [B][NI][C] float
#define OFF_V      (OFF_CSUMS + B*NI*C)   // [B][NI][HID] float
#define OFF_PERR   (OFF_V + B*NI*HID)     // [B][NI] float
#define OFF_MINK   (OFF_PERR + B*NI)      // [B] uint (mapped float, min)
#define OFF_MAXK   (OFF_MINK + B)         // [B] uint (mapped float, max)
#define OFF_VMAX   (OFF_MAXK + B)         // [B][HID] float: max_n v[n,k]
#define CTRL_END   (OFF_VMAX + B*HID)
#define OFF_HCNT   8192                   // [B][HB][NBINS] uint packed cnt|pos<<16

__device__ __host__ inline size_t off_fcnt(int hb) { return OFF_HCNT + (size_t)B * hb * NBINS; }
__device__ __host__ inline size_t off_fpos(int hb) { return off_fcnt(hb) + (size_t)B * NBINS; }
__device__ __host__ inline size_t ws_need(int hb)  { return (off_fpos(hb) + (size_t)B * NBINS) * 4; }

__device__ inline unsigned fmap(float f) {
    unsigned u = __float_as_uint(f);
    return (u & 0x80000000u) ? ~u : (u | 0x80000000u);
}
__device__ inline float funmap(unsigned k) {
    return (k & 0x80000000u) ? __uint_as_float(k & 0x7fffffffu)
                             : __uint_as_float(~k);
}

// Kernel 0: replaces 3 hipMemsetAsync dispatches.
__global__ void k_init(unsigned* wsu, float* out) {
    int i = threadIdx.x;
    for (int j = i; j < CTRL_END; j += 256) wsu[j] = 0u;
    __syncthreads();
    if (i < B) wsu[OFF_MINK + i] = 0xFFFFFFFFu;
    if (i == 0) out[0] = 0.f;
}

// Kernel 1: weighted per-instance counts and embedding sums (interior only;
// padding contributes zero because padded w == 0).
__global__ __launch_bounds__(256, 4) void k_counts(const float* __restrict__ emb,
                                                   const float* __restrict__ wgt,
                                                   const int* __restrict__ gt, float* ws) {
    __shared__ float s_cnt[NI];
    __shared__ float s_sum[NI * C];
    int tid = threadIdx.x;
    int img = blockIdx.y;
    for (int i = tid; i < NI; i += 256) s_cnt[i] = 0.f;
    for (int i = tid; i < NI * C; i += 256) s_sum[i] = 0.f;
    __syncthreads();
    int p = blockIdx.x * 256 + tid;  // 144 blocks * 256 == 36864 exactly
    int g = gt[img * INTER + p];
    if (g > 0 && g <= NI) {
        float wv = wgt[img * INTER + p];
        atomicAdd(&s_cnt[g - 1], wv);
        const float* e = emb + (size_t)img * C * INTER + p;
        #pragma unroll
        for (int c = 0; c < C; c++)
            atomicAdd(&s_sum[(g - 1) * C + c], e[c * INTER] * wv);
    }
    __syncthreads();
    for (int i = tid; i < NI; i += 256)
        atomicAdd(&ws[OFF_COUNTS + img * NI + i], s_cnt[i]);
    for (int i = tid; i < NI * C; i += 256)
        atomicAdd(&ws[OFF_CSUMS + (img * NI) * C + i], s_sum[i]);
}

// Kernel 2: v[n,k] = centers.W1 + b1; vmax[k] = max_n v[n,k]; pad-region
// error per instance: perr[n] = 1 + MLP(v[n]); fold pad errors into min/max.
__global__ void k_centers(const float* __restrict__ W1, const float* __restrict__ b1,
                          const float* __restrict__ W2, const float* __restrict__ b2,
                          float* ws, unsigned* wsu) {
    int img = blockIdx.x;
    int tid = threadIdx.x;
    __shared__ float s_v[NI * HID];
    for (int idx = tid; idx < NI * HID; idx += 256) {
        int n = idx >> 5, k = idx & 31;
        float cnt = ws[OFF_COUNTS + img * NI + n] + EPSF;
        float acc = b1[k];
        #pragma unroll
        for (int c = 0; c < C; c++)
            acc += (ws[OFF_CSUMS + (img * NI + n) * C + c] / cnt) * W1[c * HID + k];
        s_v[idx] = acc;
        ws[OFF_V + (img * NI + n) * HID + k] = acc;
    }
    __syncthreads();
    if (tid < HID) {
        float m = -1e30f;
        #pragma unroll
        for (int n = 0; n < NI; n++) m = fmaxf(m, s_v[n * HID + tid]);
        ws[OFF_VMAX + img * HID + tid] = m;
    }
    if (tid < NI) {
        float lg = b2[0];
        #pragma unroll
        for (int k = 0; k < HID; k++)
            lg += fmaxf(s_v[tid * HID + k], 0.f) * W2[k];
        float pe = 1.f + lg;           // label = 0 in padding
        ws[OFF_PERR + img * NI + tid] = pe;
        unsigned key = fmap(pe);
        atomicMin(&wsu[OFF_MINK + img], key);
        atomicMax(&wsu[OFF_MAXK + img], key);
    }
}

// Kernel 3: analytic per-pixel error bounds. All weights (W1, vmax, W2) read
// via wave-uniform global addresses -> scalar loads, no LDS staging.
__global__ __launch_bounds__(THR, 4) void k_bound(const float* __restrict__ emb,
                                                  const float* __restrict__ W1,
                                                  const float* __restrict__ W2,
                                                  const float* __restrict__ b2,
                                                  const float* __restrict__ ws,
                                                  unsigned* wsu) {
    int img = blockIdx.y, tid = threadIdx.x;
    __shared__ unsigned bmin, bmax;
    if (tid == 0) { bmin = 0xFFFFFFFFu; bmax = 0u; }
    __syncthreads();
    int p = blockIdx.x * THR + tid;   // 144 blocks * 256 == 36864
    const float* ep = emb + (size_t)img * C * INTER + p;
    const float* vmax = ws + OFF_VMAX + img * HID;
    float u[HID];
    #pragma unroll
    for (int k = 0; k < HID; k++) u[k] = 0.f;
    #pragma unroll
    for (int c = 0; c < C; c++) {
        float ev = ep[c * INTER];
        #pragma unroll
        for (int k = 0; k < HID; k++) u[k] = fmaf(ev, W1[c * HID + k], u[k]);
    }
    float b2v = b2[0];
    float hi = b2v, lo = b2v;
    #pragma unroll
    for (int k = 0; k < HID; k++) {
        float t = fmaxf(vmax[k] - u[k], 0.f);
        float w = W2[k];
        hi = fmaf(fmaxf(w, 0.f), t, hi);
        lo = fmaf(fminf(w, 0.f), t, lo);
    }
    float elo = fminf(1.f - hi, 1.f + lo);
    float ehi = fmaxf(1.f - lo, 1.f + hi);
    atomicMin(&bmin, fmap(elo));
    atomicMax(&bmax, fmap(ehi));
    __syncthreads();
    if (tid == 0) {
        atomicMin(&wsu[OFF_MINK + img], bmin);
        atomicMax(&wsu[OFF_MAXK + img], bmax);
    }
}

// Kernel 4: histogram. LDS holds ONLY the packed bin array (8 KB); v/W1/W2
// come from scalar loads (wave-uniform addresses). One LDS atomic per
// (pixel, instance): packed cnt|pos<<16 (block cnt <= 32*256 = 8192 < 2^16).
// Representative value = bin center; k_loss rebuilds sums from centers and
// keeps pad-region errors exact (jaccard total variation <= 1 bounds the
// binning error by bw/2 ~ 2e-3).
template <int HB>
__global__ __launch_bounds__(THR, 4) void k_hist(const float* __restrict__ emb,
                                                 const int* __restrict__ gt,
                                                 const float* __restrict__ W1,
                                                 const float* __restrict__ W2,
                                                 const float* __restrict__ b2,
                                                 const float* __restrict__ ws,
                                                 unsigned* wsu) {
    constexpr int PPB = INTER / HB;
    constexpr int ITER = PPB / THR;
    int img = blockIdx.y, bx = blockIdx.x, tid = threadIdx.x;
    __shared__ unsigned s_h[NBINS];   // 8 KB
    for (int i = tid; i < NBINS; i += THR) s_h[i] = 0u;
    float emax = funmap(wsu[OFF_MAXK + img]);
    float emin = funmap(wsu[OFF_MINK + img]);
    float invbw = (float)NBINS / fmaxf(emax - emin, 1e-20f);
    float b2v = b2[0];
    const float* vimg = ws + OFF_V + img * NI * HID;   // wave-uniform
    __syncthreads();

    #pragma unroll
    for (int it = 0; it < ITER; ++it) {
        int p = bx * PPB + it * THR + tid;
        const float* ep = emb + (size_t)img * C * INTER + p;
        float u[HID];
        #pragma unroll
        for (int k = 0; k < HID; k++) u[k] = 0.f;
        #pragma unroll
        for (int c = 0; c < C; c++) {
            float ev = ep[c * INTER];
            #pragma unroll
            for (int k = 0; k < HID; k++) u[k] = fmaf(ev, W1[c * HID + k], u[k]);
        }
        int g = gt[img * INTER + p];
        for (int n = 0; n < NI; n++) {
            const float* vn = vimg + n * HID;          // wave-uniform
            float lg0 = b2v, lg1 = 0.f, lg2 = 0.f, lg3 = 0.f;
            #pragma unroll
            for (int k = 0; k < HID; k += 4) {
                lg0 = fmaf(fmaxf(vn[k + 0] - u[k + 0], 0.f), W2[k + 0], lg0);
                lg1 = fmaf(fmaxf(vn[k + 1] - u[k + 1], 0.f), W2[k + 1], lg1);
                lg2 = fmaf(fmaxf(vn[k + 2] - u[k + 2], 0.f), W2[k + 2], lg2);
                lg3 = fmaf(fmaxf(vn[k + 3] - u[k + 3], 0.f), W2[k + 3], lg3);
            }
            float lg = (lg0 + lg1) + (lg2 + lg3);
            bool pos = (g == n + 1);
            float err = pos ? (1.f - lg) : (1.f + lg);
            int bn = (int)((emax - err) * invbw);
            bn = bn < 0 ? 0 : (bn >= NBINS ? NBINS - 1 : bn);
            atomicAdd(&s_h[bn], pos ? 0x10001u : 1u);
        }
    }
    __syncthreads();
    unsigned* gc = wsu + OFF_HCNT + (size_t)(img * HB + bx) * NBINS;
    for (int i = tid; i < NBINS; i += THR) gc[i] = s_h[i];
}

// Kernel 5: collapse the hb partial histograms into one per image (coalesced).
__global__ void k_reduce(unsigned* wsu, int hb) {
    int img = blockIdx.y;
    int bn = blockIdx.x * 256 + threadIdx.x;
    unsigned cnt = 0, pos = 0;
    for (int r = 0; r < hb; r++) {
        unsigned pk = wsu[OFF_HCNT + (size_t)(img * hb + r) * NBINS + bn];
        cnt += pk & 0xFFFFu;
        pos += pk >> 16;
    }
    wsu[off_fcnt(hb) + (size_t)img * NBINS + bn] = cnt;
    wsu[off_fpos(hb) + (size_t)img * NBINS + bn] = pos;
}

// Kernel 6: per-image -- seed per-bin sums from bin centers, add pad
// contributions EXACTLY, prefix scan, Lovasz loss in double.
__global__ void k_loss(const float* ws, const unsigned* wsu, float* out, int hb) {
    const int T = 256;
    const int CHUNK = NBINS / T;  // 8
    int img = blockIdx.x, tid = threadIdx.x;
    __shared__ unsigned s_cnt[NBINS], s_pos[NBINS];  // 16 KB
    __shared__ float s_sum[NBINS];                   // 8 KB
    __shared__ unsigned s_pc[T], s_pp[T];
    __shared__ double s_a[T];

    float emax = funmap(wsu[OFF_MAXK + img]);
    float emin = funmap(wsu[OFF_MINK + img]);
    float bw = (emax - emin) / (float)NBINS;
    float invbw = (float)NBINS / fmaxf(emax - emin, 1e-20f);

    for (int i = tid; i < NBINS; i += T) {
        unsigned cnt = wsu[off_fcnt(hb) + (size_t)img * NBINS + i];
        s_cnt[i] = cnt;
        s_pos[i] = wsu[off_fpos(hb) + (size_t)img * NBINS + i];
        float center = emax - ((float)i + 0.5f) * bw;
        s_sum[i] = (float)cnt * fmaxf(center, 0.f);
    }
    __syncthreads();

    // pad-region: each (img,n) pad error occurs PADMULT times, label 0; exact.
    if (tid < NI) {
        float pe = ws[OFF_PERR + img * NI + tid];
        int bn = (int)((emax - pe) * invbw);
        bn = bn < 0 ? 0 : (bn >= NBINS ? NBINS - 1 : bn);
        atomicAdd(&s_cnt[bn], (unsigned)PADMULT);
        atomicAdd(&s_sum[bn], (float)PADMULT * fmaxf(pe, 0.f));
    }
    __syncthreads();

    // per-thread chunk totals, then Hillis-Steele inclusive scan
    unsigned ccnt = 0, cpos = 0;
    for (int j = 0; j < CHUNK; j++) {
        int bn = tid * CHUNK + j;
        ccnt += s_cnt[bn]; cpos += s_pos[bn];
    }
    s_pc[tid] = ccnt; s_pp[tid] = cpos;
    __syncthreads();
    for (int off = 1; off < T; off <<= 1) {
        unsigned ac = 0, ap = 0;
        if (tid >= off) { ac = s_pc[tid - off]; ap = s_pp[tid - off]; }
        __syncthreads();
        s_pc[tid] += ac; s_pp[tid] += ap;
        __syncthreads();
    }
    double Gd = (double)s_pp[T - 1];
    double r = (double)(s_pc[tid] - ccnt), L = (double)(s_pp[tid] - cpos);

    double Jprev = 1.0 - (Gd - L) / (Gd + r - L);
    double acc = 0.0;
    for (int j = 0; j < CHUNK; j++) {
        int bn = tid * CHUNK + j;
        unsigned cv = s_cnt[bn], pv = s_pos[bn];
        if (cv) {
            r += (double)cv; L += (double)pv;
            double J = 1.0 - (Gd - L) / (Gd + r - L);
            double mean = (double)s_sum[bn] / (double)cv;
            acc += mean * (J - Jprev);
            Jprev = J;
        }
    }
    s_a[tid] = acc;
    __syncthreads();
    for (int s = T / 2; s > 0; s >>= 1) {
        if (tid < s) s_a[tid] += s_a[tid + s];
        __syncthreads();
    }
    if (tid == 0) atomicAdd(out, (float)(s_a[0] * 0.25));  // mean over B=4
}

extern "C" void kernel_launch(void* const* d_in, const int* in_sizes, int n_in,
                              void* d_out, int out_size, void* d_ws, size_t ws_size,
                              hipStream_t stream) {
    const float* emb = (const float*)d_in[0];
    const float* wgt = (const float*)d_in[1];
    const int*   gt  = (const int*)d_in[2];
    const float* W1  = (const float*)d_in[3];
    const float* b1  = (const float*)d_in[4];
    const float* W2  = (const float*)d_in[5];
    const float* b2  = (const float*)d_in[6];
    float* out = (float*)d_out;
    float* ws  = (float*)d_ws;
    unsigned* wsu = (unsigned*)d_ws;

    // HB=144 needs ~4.8 MB of ws (proven safe >= 4.85 MB in round 2);
    // fall back to HB=72 (2.4 MB) if scratch is small. Deterministic.
    int hb = (ws_size >= ws_need(144)) ? 144 : 72;

    k_init<<<1, 256, 0, stream>>>(wsu, out);
    dim3 g1(INTER / 256, B);
    k_counts<<<g1, 256, 0, stream>>>(emb, wgt, gt, ws);
    k_centers<<<B, 256, 0, stream>>>(W1, b1, W2, b2, ws, wsu);
    dim3 gb(INTER / THR, B);
    k_bound<<<gb, THR, 0, stream>>>(emb, W1, W2, b2, ws, wsu);
    if (hb == 144) {
        dim3 gh(144, B);
        k_hist<144><<<gh, THR, 0, stream>>>(emb, gt, W1, W2, b2, ws, wsu);
    } else {
        dim3 gh(72, B);
        k_hist<72><<<gh, THR, 0, stream>>>(emb, gt, W1, W2, b2, ws, wsu);
    }
    dim3 gr(NBINS / 256, B);
    k_reduce<<<gr, 256, 0, stream>>>(wsu, hb);
    k_loss<<<B, 256, 0, stream>>>(ws, wsu, out, hb);
}